// Round 2
// baseline (431.551 us; speedup 1.0000x reference)
//
#include <hip/hip_runtime.h>

// Problem dims (fixed by setup_inputs)
#define D_  160
#define H_  192
#define W_  160
#define HW_ (H_*W_)          // 30720
#define N_  (D_*HW_)         // 4915200

#define SEGH 48              // H_/4 segments per column in pass AB
#define SEGD 40              // D_/4 segments per column in pass C

// ---------------------------------------------------------------- reductions
__device__ __forceinline__ float blockReduceSum(float v) {
    __shared__ float red_s[16];
    const int lane = threadIdx.x & 63;
    const int wid  = threadIdx.x >> 6;
    #pragma unroll
    for (int off = 32; off > 0; off >>= 1) v += __shfl_down(v, off, 64);
    __syncthreads();                  // protect red_s across repeated calls
    if (lane == 0) red_s[wid] = v;
    __syncthreads();
    const int nw = (blockDim.x + 63) >> 6;
    v = (threadIdx.x < nw) ? red_s[threadIdx.x] : 0.0f;
    if (wid == 0) {
        #pragma unroll
        for (int off = 8; off > 0; off >>= 1) v += __shfl_down(v, off, 64);
    }
    return v;  // valid on thread 0
}

// ------------------------------------------------- 9-tap W-sum of the 5 fields
__device__ __forceinline__ void wsum5(const float* __restrict__ I,
                                      const float* __restrict__ J,
                                      int rowbase, int w, float out[5]) {
    float sI = 0.f, sJ = 0.f, sII = 0.f, sJJ = 0.f, sIJ = 0.f;
    #pragma unroll
    for (int o = -4; o <= 4; ++o) {
        int x = w + o;
        if (x >= 0 && x < W_) {
            float a = I[rowbase + x];
            float b = J[rowbase + x];
            sI  += a;     sJ  += b;
            sII += a * a; sJJ += b * b; sIJ += a * b;
        }
    }
    out[0] = sI; out[1] = sJ; out[2] = sII; out[3] = sJJ; out[4] = sIJ;
}

// --------------------------------------------- pass AB: box-sum along W then H
// thread <-> (d, w, seg). Slides a 9-row register ring along H.
// out: 5 volumes (SoA) of W+H box sums.
__global__ void __launch_bounds__(256)
passAB(const float* __restrict__ I, const float* __restrict__ J,
       float* __restrict__ out) {
    int gtid = blockIdx.x * 256 + threadIdx.x;   // 102400 total, grid exact
    int w    = gtid % W_;
    int t    = gtid / W_;
    int d    = t % D_;
    int seg  = t / D_;
    int h0   = seg * SEGH;
    int dbase = d * HW_;

    float r[9][5];
    float s[5] = {0.f, 0.f, 0.f, 0.f, 0.f};
    #pragma unroll
    for (int k = 0; k < 9; ++k) {
        int y = h0 - 4 + k;
        if (y >= 0 && y < H_) {
            wsum5(I, J, dbase + y * W_, w, r[k]);
        } else {
            #pragma unroll
            for (int f = 0; f < 5; ++f) r[k][f] = 0.f;
        }
        #pragma unroll
        for (int f = 0; f < 5; ++f) s[f] += r[k][f];
    }

    for (int h = h0; h < h0 + SEGH; ++h) {
        int idx = dbase + h * W_ + w;
        #pragma unroll
        for (int f = 0; f < 5; ++f) out[f * N_ + idx] = s[f];

        float wnew[5];
        int y = h + 5;
        if (y < H_) {
            wsum5(I, J, dbase + y * W_, w, wnew);
        } else {
            #pragma unroll
            for (int f = 0; f < 5; ++f) wnew[f] = 0.f;
        }
        #pragma unroll
        for (int f = 0; f < 5; ++f) s[f] += wnew[f] - r[0][f];
        #pragma unroll
        for (int k = 0; k < 8; ++k) {
            #pragma unroll
            for (int f = 0; f < 5; ++f) r[k][f] = r[k + 1][f];
        }
        #pragma unroll
        for (int f = 0; f < 5; ++f) r[8][f] = wnew[f];
    }
}

// ------------------------------------- pass C: box-sum along D + cc + reduce
// thread <-> (h, w, seg). Sliding window along D (add leading, sub trailing).
__global__ void __launch_bounds__(256)
passC(const float* __restrict__ in, float* __restrict__ accum) {
    int gtid = blockIdx.x * 256 + threadIdx.x;   // 122880 total, grid exact
    int w    = gtid % W_;
    int t    = gtid / W_;
    int h    = t % H_;
    int seg  = t / H_;
    int d0   = seg * SEGD;
    int base = h * W_ + w;

    float s[5] = {0.f, 0.f, 0.f, 0.f, 0.f};
    #pragma unroll
    for (int f = 0; f < 5; ++f) {
        for (int z = d0 - 4; z <= d0 + 4; ++z) {
            if (z >= 0 && z < D_) s[f] += in[f * N_ + z * HW_ + base];
        }
    }

    const float inv = 1.0f / 729.0f;
    float acc = 0.0f;
    for (int d = d0; d < d0 + SEGD; ++d) {
        float sI = s[0], sJ = s[1], sII = s[2], sJJ = s[3], sIJ = s[4];
        float u_I = sI * inv, u_J = sJ * inv;
        float cross = sIJ - u_J * sI - u_I * sJ + u_I * u_J * 729.0f;
        float Ivar  = sII - 2.0f * u_I * sI + u_I * u_I * 729.0f;
        float Jvar  = sJJ - 2.0f * u_J * sJ + u_J * u_J * 729.0f;
        float cc = cross * cross / (Ivar * Jvar + 1e-5f);
        acc += cc;

        int za = d + 5, zb = d - 4;
        #pragma unroll
        for (int f = 0; f < 5; ++f) {
            float add = (za < D_)  ? in[f * N_ + za * HW_ + base] : 0.f;
            float sub = (zb >= 0)  ? in[f * N_ + zb * HW_ + base] : 0.f;
            s[f] += add - sub;
        }
    }

    float tot = blockReduceSum(acc);
    if (threadIdx.x == 0) atomicAdd(&accum[0], tot);
}

// ------------------------------------------------------ gradient (l2) penalty
__global__ void __launch_bounds__(256)
gradK(const float* __restrict__ s, float* __restrict__ accum) {
    float ax = 0.f, ay = 0.f, az = 0.f;   // H-diff, D-diff, W-diff
    const int total = 3 * N_;
    for (int idx = blockIdx.x * 256 + threadIdx.x; idx < total;
         idx += gridDim.x * 256) {
        int i2 = idx % N_;
        int d  = i2 / HW_;
        int r  = i2 % HW_;
        int h  = r / W_;
        int w  = r % W_;
        float c = s[idx];
        if (w < W_ - 1) { float t = s[idx + 1]   - c; az += t * t; }
        if (h < H_ - 1) { float t = s[idx + W_]  - c; ax += t * t; }
        if (d < D_ - 1) { float t = s[idx + HW_] - c; ay += t * t; }
    }
    ax = blockReduceSum(ax);
    ay = blockReduceSum(ay);
    az = blockReduceSum(az);
    if (threadIdx.x == 0) {
        atomicAdd(&accum[1], ax);
        atomicAdd(&accum[2], ay);
        atomicAdd(&accum[3], az);
    }
}

// ------------------------------------------------------------- final combine
__global__ void finalK(const float* __restrict__ accum, float* __restrict__ out) {
    const float Ncc = (float)N_;
    // 3 displacement channels: diff counts include the channel dimension!
    const float Nx  = (float)(3 * D_ * (H_ - 1) * W_);   // H-diff count
    const float Ny  = (float)(3 * (D_ - 1) * H_ * W_);   // D-diff count
    const float Nz  = (float)(3 * D_ * H_ * (W_ - 1));   // W-diff count
    float cc_mean = accum[0] / Ncc;
    float gd = accum[1] / Nx + accum[2] / Ny + accum[3] / Nz;
    out[0] = (1.0f - cc_mean) + 0.01f * gd / 3.0f;
}

// ---------------------------------------------------------------------- launch
extern "C" void kernel_launch(void* const* d_in, const int* in_sizes, int n_in,
                              void* d_out, int out_size, void* d_ws, size_t ws_size,
                              hipStream_t stream) {
    const float* I   = (const float*)d_in[0];   // y_fwd  (N_)
    const float* J   = (const float*)d_in[1];   // y_inv  (N_)
    const float* dsp = (const float*)d_in[2];   // dsp_fields (3*N_)
    float* out = (float*)d_out;

    float* bufB  = (float*)d_ws;                 // 5 * N_ floats (~98.3 MB)
    float* accum = bufB + (size_t)5 * N_;        // 4 floats

    hipMemsetAsync(accum, 0, 4 * sizeof(float), stream);

    // pass AB: 160*160*4 threads / 256 = 400 blocks (exact)
    passAB<<<400, 256, 0, stream>>>(I, J, bufB);
    // pass C: 192*160*4 threads / 256 = 480 blocks (exact)
    passC<<<480, 256, 0, stream>>>(bufB, accum);
    // gradient penalty
    gradK<<<2048, 256, 0, stream>>>(dsp, accum);
    // combine
    finalK<<<1, 1, 0, stream>>>(accum, out);
}